// Round 12
// baseline (72.547 us; speedup 1.0000x reference)
//
#include <hip/hip_runtime.h>

#ifndef __has_builtin
#define __has_builtin(x) 0
#endif

__device__ __forceinline__ float fexp2(float x) {
#if __has_builtin(__builtin_amdgcn_exp2f)
    return __builtin_amdgcn_exp2f(x);
#else
    return exp2f(x);
#endif
}
__device__ __forceinline__ float frcp(float x) {
#if __has_builtin(__builtin_amdgcn_rcpf)
    return __builtin_amdgcn_rcpf(x);
#else
    return 1.0f / x;
#endif
}

constexpr int TT = 32;    // directions T
constexpr int SS = 32;    // steps S
constexpr int BB = 64;    // graphs B
constexpr int NB = 64;    // partition blocks for edge sort
constexpr int CPB_N = 8;  // chunks per graph, node part
constexpr int CPB_E = 16; // chunks per graph, edge part
constexpr int REP = 5;    // edge_k amplification factor (counters attribution)
constexpr float FL = 50.0f * 1.44269504088896340736f;  // steepness * log2(e)
constexpr float QS = 65536.0f;                          // fixed-point scale 2^16
constexpr float IQS = 1.0f / 65536.0f;
constexpr float IQR = IQS / (float)REP;
constexpr float RR  = 1.0f / (float)REP;

// ---- prep: bounds + out-zero + edge hist (also emits ge[e] = graph of edge) ----
__global__ __launch_bounds__(256) void prep_k(
    const int* __restrict__ batch, const int* __restrict__ src,
    int N, int E, int nB,
    int* __restrict__ starts, int* __restrict__ hist,
    int* __restrict__ ge, float* __restrict__ out)
{
    if ((int)blockIdx.x < nB) {
        const int n = blockIdx.x * 256 + threadIdx.x;
        if (n >= N) return;
        const int g = batch[n];
        const int gp = (n == 0) ? -1 : batch[n - 1];
        for (int g2 = gp + 1; g2 <= g; ++g2) starts[g2] = n;
        if (n == N - 1)
            for (int g2 = g + 1; g2 <= BB; ++g2) starts[g2] = N;
    } else {
        const int b = blockIdx.x - nB;      // 0..NB-1
        float4* o4 = (float4*)(out + (size_t)b * SS * TT);
        o4[threadIdx.x] = float4{0.f, 0.f, 0.f, 0.f};
        __shared__ int h[BB];
        if (threadIdx.x < BB) h[threadIdx.x] = 0;
        __syncthreads();
        const int per = (E + NB - 1) / NB;
        const int lo = b * per, hi = min(E, lo + per);
        for (int e = lo + threadIdx.x; e < hi; e += 256) {
            const int g = batch[src[e]];
            ge[e] = g;
            atomicAdd(&h[g], 1);
        }
        __syncthreads();
        if (threadIdx.x < BB) hist[b * BB + threadIdx.x] = h[threadIdx.x];
    }
}

// ---- ECT core (node): window-3 sigmoid + histogram suffix, u32 LDS atomics ----
__device__ __forceinline__ void ect_core(
    const float* __restrict__ x, const float* __restrict__ v,
    const float* __restrict__ lin,
    int lo, int hi, int g, float sign, float* __restrict__ out)
{
    __shared__ unsigned accS[TT][SS + 1];
    __shared__ unsigned cntS[TT][SS + 1];
    __shared__ unsigned part[TT][9];
    for (int i = threadIdx.x; i < TT * (SS + 1); i += 256) {
        ((unsigned*)accS)[i] = 0u;
        ((unsigned*)cntS)[i] = 0u;
    }
    const int t = threadIdx.x & 31;
    const int pr = threadIdx.x >> 5;
    const float v0 = v[t], v1 = v[TT + t], v2 = v[2 * TT + t];
    const float l0 = lin[0];
    const float dS = lin[1] - l0;
    const float invD = frcp(dS);
    const float fld = FL * dS;                 // ~5.12 exp2-units per bin
    const float pm1 = fexp2(fld), pp1 = fexp2(-fld);
    __syncthreads();

    for (int p = lo + pr; p < hi; p += 8) {
        const float h = fmaf(x[3 * p], v0, fmaf(x[3 * p + 1], v1, x[3 * p + 2] * v2));
        const float hl0 = h - l0;
        float fj = rintf(hl0 * invD);
        fj = fminf(34.f, fmaxf(-2.f, fj));
        const int j = (int)fj;
        const float delta = fmaf(-fj, dS, hl0);   // h - l_j
        const float ucen = fexp2(FL * delta);     // in [0.17, 5.9] when unclamped
        const unsigned q0 = __float2uint_rn(QS * frcp(fmaf(ucen, pm1, 1.f))); // s=j-1
        const unsigned q1 = __float2uint_rn(QS * frcp(1.f + ucen));           // s=j
        const unsigned q2 = __float2uint_rn(QS * frcp(fmaf(ucen, pp1, 1.f))); // s=j+1
        const int b = j + 2;
        if (b < SS) atomicAdd(&cntS[t][b], 1u);
        if (1 <= j && j <= SS) atomicAdd(&accS[t][j - 1], q0);
        if (0 <= j && j < SS)  atomicAdd(&accS[t][j], q1);
        if (-1 <= j && j < SS - 1) atomicAdd(&accS[t][j + 1], q2);
    }
    __syncthreads();
    const unsigned c0 = cntS[t][4 * pr], c1 = cntS[t][4 * pr + 1];
    const unsigned c2 = cntS[t][4 * pr + 2], c3 = cntS[t][4 * pr + 3];
    part[t][pr + 1] = c0 + c1 + c2 + c3;
    if (pr == 0) part[t][0] = 0u;
    __syncthreads();
    if (pr == 0) {
        unsigned r = 0u;
#pragma unroll
        for (int q = 1; q <= 8; ++q) { r += part[t][q]; part[t][q] = r; }
    }
    __syncthreads();
    unsigned run = part[t][pr];
    float* o = out + (size_t)g * SS * TT;
    run += c0;
    atomicAdd(&o[(4 * pr + 0) * TT + t], sign * fmaf((float)accS[t][4 * pr + 0], IQS, (float)run));
    run += c1;
    atomicAdd(&o[(4 * pr + 1) * TT + t], sign * fmaf((float)accS[t][4 * pr + 1], IQS, (float)run));
    run += c2;
    atomicAdd(&o[(4 * pr + 2) * TT + t], sign * fmaf((float)accS[t][4 * pr + 2], IQS, (float)run));
    run += c3;
    atomicAdd(&o[(4 * pr + 3) * TT + t], sign * fmaf((float)accS[t][4 * pr + 3], IQS, (float)run));
}

// ---- k2: scatter blocks (0..NB-1, reading precomputed ge) ∥ node-ect blocks ----
__global__ __launch_bounds__(256) void mid_k(
    const float* __restrict__ x, const float* __restrict__ v,
    const float* __restrict__ lin,
    const int* __restrict__ src, const int* __restrict__ dst,
    const int* __restrict__ ge, int E,
    const int* __restrict__ hist, int* __restrict__ offs,
    int2* __restrict__ epair,
    const int* __restrict__ starts, float* __restrict__ out)
{
    if ((int)blockIdx.x < NB) {
        __shared__ int lcur[BB];
        __shared__ int stot[BB];
        const int tid = threadIdx.x;
        if (tid < BB) {
            int accb = 0, tot = 0;
            for (int b = 0; b < NB; ++b) {
                const int hv = hist[b * BB + tid];
                accb += (b < (int)blockIdx.x) ? hv : 0;
                tot += hv;
            }
            lcur[tid] = accb;
            stot[tid] = tot;
        }
        __syncthreads();
        if (tid == 0) {
            int run = 0;
            for (int i = 0; i < BB; ++i) { const int tv = stot[i]; stot[i] = run; run += tv; }
            if (blockIdx.x == 0) offs[BB] = run;
        }
        __syncthreads();
        if (tid < BB) {
            lcur[tid] += stot[tid];
            if (blockIdx.x == 0) offs[tid] = stot[tid];
        }
        __syncthreads();
        const int per = (E + NB - 1) / NB;
        const int lo = blockIdx.x * per, hi = min(E, lo + per);
        for (int e = lo + tid; e < hi; e += 256) {
            const int pos = atomicAdd(&lcur[ge[e]], 1);
            epair[pos] = int2{src[e], dst[e]};
        }
    } else {
        const int bid = blockIdx.x - NB;
        const int g = bid / CPB_N, c = bid % CPB_N;
        const int s0 = starts[g], s1 = starts[g + 1];
        const int chunk = (s1 - s0 + CPB_N - 1) / CPB_N;
        const int lo = s0 + c * chunk;
        const int hi = min(s1, lo + chunk);
        ect_core(x, v, lin, lo, hi, g, 1.0f, out);
    }
}

// ---- k3: edge-ect, REP-amplified for counter attribution ----
// Accumulation loop runs REP times into the same LDS accumulators; epilogue
// scales by 1/REP -> output identical (cnt <= 500, acc <= 32M: exact enough).
__global__ __launch_bounds__(256) void edge_k(
    const float* __restrict__ x, const float* __restrict__ v,
    const float* __restrict__ lin, const int2* __restrict__ epair,
    const int* __restrict__ offs, float* __restrict__ out)
{
    __shared__ unsigned accS[TT][SS + 1];
    __shared__ unsigned cntS[TT][SS + 1];
    __shared__ unsigned part[TT][9];
    for (int i = threadIdx.x; i < TT * (SS + 1); i += 256) {
        ((unsigned*)accS)[i] = 0u;
        ((unsigned*)cntS)[i] = 0u;
    }
    const int g = blockIdx.x / CPB_E, c = blockIdx.x % CPB_E;
    const int s0 = offs[g], s1 = offs[g + 1];
    const int chunk = (s1 - s0 + CPB_E - 1) / CPB_E;
    const int lo = s0 + c * chunk;
    const int hi = min(s1, lo + chunk);

    const int t = threadIdx.x & 31;
    const int pr = threadIdx.x >> 5;
    const float v0 = v[t], v1 = v[TT + t], v2 = v[2 * TT + t];
    const float l0 = lin[0];
    const float dS = lin[1] - l0;
    const float invD = frcp(dS);
    const float fld = FL * dS;
    const float pm1 = fexp2(fld), pp1 = fexp2(-fld);
    __syncthreads();

    for (int r = 0; r < REP; ++r) {
        for (int p = lo + pr; p < hi; p += 8) {
            const int2 ed = epair[p];
            const float hs = fmaf(x[3 * ed.x], v0, fmaf(x[3 * ed.x + 1], v1, x[3 * ed.x + 2] * v2));
            const float hd = fmaf(x[3 * ed.y], v0, fmaf(x[3 * ed.y + 1], v1, x[3 * ed.y + 2] * v2));
            const float h = fmaxf(hs, hd);
            const float hl0 = h - l0;
            float fj = rintf(hl0 * invD);
            fj = fminf(34.f, fmaxf(-2.f, fj));
            const int j = (int)fj;
            const float delta = fmaf(-fj, dS, hl0);
            const float ucen = fexp2(FL * delta);
            const unsigned q0 = __float2uint_rn(QS * frcp(fmaf(ucen, pm1, 1.f)));
            const unsigned q1 = __float2uint_rn(QS * frcp(1.f + ucen));
            const unsigned q2 = __float2uint_rn(QS * frcp(fmaf(ucen, pp1, 1.f)));
            const int b = j + 2;
            if (b < SS) atomicAdd(&cntS[t][b], 1u);
            if (1 <= j && j <= SS) atomicAdd(&accS[t][j - 1], q0);
            if (0 <= j && j < SS)  atomicAdd(&accS[t][j], q1);
            if (-1 <= j && j < SS - 1) atomicAdd(&accS[t][j + 1], q2);
        }
    }
    __syncthreads();
    const unsigned c0 = cntS[t][4 * pr], c1 = cntS[t][4 * pr + 1];
    const unsigned c2 = cntS[t][4 * pr + 2], c3 = cntS[t][4 * pr + 3];
    part[t][pr + 1] = c0 + c1 + c2 + c3;
    if (pr == 0) part[t][0] = 0u;
    __syncthreads();
    if (pr == 0) {
        unsigned r = 0u;
#pragma unroll
        for (int q = 1; q <= 8; ++q) { r += part[t][q]; part[t][q] = r; }
    }
    __syncthreads();
    unsigned run = part[t][pr];
    float* o = out + (size_t)g * SS * TT;
    run += c0;
    atomicAdd(&o[(4 * pr + 0) * TT + t], -fmaf((float)accS[t][4 * pr + 0], IQR, (float)run * RR));
    run += c1;
    atomicAdd(&o[(4 * pr + 1) * TT + t], -fmaf((float)accS[t][4 * pr + 1], IQR, (float)run * RR));
    run += c2;
    atomicAdd(&o[(4 * pr + 2) * TT + t], -fmaf((float)accS[t][4 * pr + 2], IQR, (float)run * RR));
    run += c3;
    atomicAdd(&o[(4 * pr + 3) * TT + t], -fmaf((float)accS[t][4 * pr + 3], IQR, (float)run * RR));
}

extern "C" void kernel_launch(void* const* d_in, const int* in_sizes, int n_in,
                              void* d_out, int out_size, void* d_ws, size_t ws_size,
                              hipStream_t stream) {
    const float* x   = (const float*)d_in[0];
    const float* v   = (const float*)d_in[1];
    const float* lin = (const float*)d_in[2];
    const int* edge_index = (const int*)d_in[3];
    const int* batch = (const int*)d_in[4];

    const int N = in_sizes[0] / 3;
    const int E = in_sizes[3] / 2;
    const int* src = edge_index;       // edge_index[0][:]
    const int* dst = edge_index + E;   // edge_index[1][:]
    float* out = (float*)d_out;

    char* ws = (char*)d_ws;
    int* starts = (int*)ws;                                   // 65 ints
    int* offs   = (int*)(ws + 512);                           // 65 ints
    int* hist   = (int*)(ws + 1024);                          // NB*BB ints (16 KB)
    int* ge     = (int*)(ws + 65536);                         // E ints
    int2* epair = (int2*)(ws + 65536 + (((size_t)E * 4 + 255) / 256) * 256);  // E int2

    const int nB = (N + 255) / 256;
    prep_k<<<nB + NB, 256, 0, stream>>>(batch, src, N, E, nB, starts, hist, ge, out);
    mid_k<<<NB + BB * CPB_N, 256, 0, stream>>>(x, v, lin, src, dst, ge, E,
                                               hist, offs, epair, starts, out);
    edge_k<<<BB * CPB_E, 256, 0, stream>>>(x, v, lin, epair, offs, out);
}

// Round 13
// 34.555 us; speedup vs baseline: 2.0995x; 2.0995x over previous
//
#include <hip/hip_runtime.h>

#ifndef __has_builtin
#define __has_builtin(x) 0
#endif

__device__ __forceinline__ float fexp2(float x) {
#if __has_builtin(__builtin_amdgcn_exp2f)
    return __builtin_amdgcn_exp2f(x);
#else
    return exp2f(x);
#endif
}
__device__ __forceinline__ float frcp(float x) {
#if __has_builtin(__builtin_amdgcn_rcpf)
    return __builtin_amdgcn_rcpf(x);
#else
    return 1.0f / x;
#endif
}

constexpr int TT = 32;    // directions T
constexpr int SS = 32;    // steps S
constexpr int BB = 64;    // graphs B
constexpr int NB = 64;    // partition blocks for edge sort
constexpr int CPB_N = 8;  // chunks per graph, node part
constexpr int CPB_E = 16; // chunks per graph, edge part
constexpr int LUTN = 1024; // sigmoid-window LUT bins over frac in [-1/2, 1/2]
constexpr float FL = 50.0f * 1.44269504088896340736f;  // steepness * log2(e)
constexpr float QS = 65536.0f;                          // fixed-point scale 2^16
constexpr float IQS = 1.0f / 65536.0f;

// ---- prep: bounds + out-zero + edge hist (also emits ge[e] = graph of edge) ----
__global__ __launch_bounds__(256) void prep_k(
    const int* __restrict__ batch, const int* __restrict__ src,
    int N, int E, int nB,
    int* __restrict__ starts, int* __restrict__ hist,
    int* __restrict__ ge, float* __restrict__ out)
{
    if ((int)blockIdx.x < nB) {
        const int n = blockIdx.x * 256 + threadIdx.x;
        if (n >= N) return;
        const int g = batch[n];
        const int gp = (n == 0) ? -1 : batch[n - 1];
        for (int g2 = gp + 1; g2 <= g; ++g2) starts[g2] = n;
        if (n == N - 1)
            for (int g2 = g + 1; g2 <= BB; ++g2) starts[g2] = N;
    } else {
        const int b = blockIdx.x - nB;      // 0..NB-1
        float4* o4 = (float4*)(out + (size_t)b * SS * TT);
        o4[threadIdx.x] = float4{0.f, 0.f, 0.f, 0.f};
        __shared__ int h[BB];
        if (threadIdx.x < BB) h[threadIdx.x] = 0;
        __syncthreads();
        const int per = (E + NB - 1) / NB;
        const int lo = b * per, hi = min(E, lo + per);
        for (int e = lo + threadIdx.x; e < hi; e += 256) {
            const int g = batch[src[e]];
            ge[e] = g;
            atomicAdd(&h[g], 1);
        }
        __syncthreads();
        if (threadIdx.x < BB) hist[b * BB + threadIdx.x] = h[threadIdx.x];
    }
}

// ---- ECT core: window-3 sigmoid via LDS LUT + histogram suffix, u32 LDS atomics ----
// Per (point,t): u = (h-l0)/dS; j = rint(u); frac = u-j selects a LUT entry
// holding the three 16-bit-quantized sigmoids (s = j-1, j, j+1); all s >= j+2
// get +1 via cnt histogram, prefix-summed in the epilogue.
__device__ __forceinline__ void ect_core(
    const float* __restrict__ x, const float* __restrict__ v,
    const float* __restrict__ lin, const int2* __restrict__ epair,
    bool edge, int lo, int hi, int g, float sign, float* __restrict__ out)
{
    __shared__ unsigned accS[TT][SS + 1];
    __shared__ unsigned cntS[TT][SS + 1];
    __shared__ unsigned part[TT][9];
    __shared__ unsigned long long lut[LUTN];
    for (int i = threadIdx.x; i < TT * (SS + 1); i += 256) {
        ((unsigned*)accS)[i] = 0u;
        ((unsigned*)cntS)[i] = 0u;
    }
    const int t = threadIdx.x & 31;
    const int pr = threadIdx.x >> 5;
    const float v0 = v[t], v1 = v[TT + t], v2 = v[2 * TT + t];
    const float l0 = lin[0];
    const float dS = lin[1] - l0;
    const float invD = frcp(dS);
    const float fld = FL * dS;                 // ~5.12 exp2-units per bin
    const float pm1 = fexp2(fld), pp1 = fexp2(-fld);
    // build LUT: bin center frac_c = (b - (LUTN/2 - 0.5)) / LUTN, delta = frac_c*dS
    for (int b = threadIdx.x; b < LUTN; b += 256) {
        const float delta = ((float)b - ((float)(LUTN / 2) - 0.5f)) * (dS / (float)LUTN);
        const float ucen = fexp2(FL * delta);
        const unsigned q0 = __float2uint_rn(QS * frcp(fmaf(ucen, pm1, 1.f))); // s=j-1
        const unsigned q1 = __float2uint_rn(QS * frcp(1.f + ucen));           // s=j
        const unsigned q2 = __float2uint_rn(QS * frcp(fmaf(ucen, pp1, 1.f))); // s=j+1
        lut[b] = (unsigned long long)q0 | ((unsigned long long)q1 << 16)
               | ((unsigned long long)q2 << 32);
    }
    __syncthreads();

    for (int p = lo + pr; p < hi; p += 8) {
        float h;
        if (edge) {
            const int2 ed = epair[p];
            const float hs = fmaf(x[3 * ed.x], v0, fmaf(x[3 * ed.x + 1], v1, x[3 * ed.x + 2] * v2));
            const float hd = fmaf(x[3 * ed.y], v0, fmaf(x[3 * ed.y + 1], v1, x[3 * ed.y + 2] * v2));
            h = fmaxf(hs, hd);
        } else {
            h = fmaf(x[3 * p], v0, fmaf(x[3 * p + 1], v1, x[3 * p + 2] * v2));
        }
        const float u = (h - l0) * invD;
        float fj = rintf(u);
        fj = fminf(34.f, fmaxf(-2.f, fj));
        const int j = (int)fj;
        int bin = (int)fmaf(u - fj, (float)LUTN, (float)(LUTN / 2));
        bin = max(0, min(LUTN - 1, bin));
        const unsigned long long pk = lut[bin];
        const int b = j + 2;
        if (b < SS) atomicAdd(&cntS[t][b], 1u);
        if (1 <= j && j <= SS) atomicAdd(&accS[t][j - 1], (unsigned)(pk & 0xffffu));
        if (0 <= j && j < SS)  atomicAdd(&accS[t][j], (unsigned)((pk >> 16) & 0xffffu));
        if (-1 <= j && j < SS - 1) atomicAdd(&accS[t][j + 1], (unsigned)(pk >> 32));
    }
    __syncthreads();
    // two-level scan: thread (t, q=pr) owns s in [4q, 4q+4)
    const unsigned c0 = cntS[t][4 * pr], c1 = cntS[t][4 * pr + 1];
    const unsigned c2 = cntS[t][4 * pr + 2], c3 = cntS[t][4 * pr + 3];
    part[t][pr + 1] = c0 + c1 + c2 + c3;
    if (pr == 0) part[t][0] = 0u;
    __syncthreads();
    if (pr == 0) {
        unsigned r = 0u;
#pragma unroll
        for (int q = 1; q <= 8; ++q) { r += part[t][q]; part[t][q] = r; }
    }
    __syncthreads();
    unsigned run = part[t][pr];
    float* o = out + (size_t)g * SS * TT;
    run += c0;
    atomicAdd(&o[(4 * pr + 0) * TT + t], sign * fmaf((float)accS[t][4 * pr + 0], IQS, (float)run));
    run += c1;
    atomicAdd(&o[(4 * pr + 1) * TT + t], sign * fmaf((float)accS[t][4 * pr + 1], IQS, (float)run));
    run += c2;
    atomicAdd(&o[(4 * pr + 2) * TT + t], sign * fmaf((float)accS[t][4 * pr + 2], IQS, (float)run));
    run += c3;
    atomicAdd(&o[(4 * pr + 3) * TT + t], sign * fmaf((float)accS[t][4 * pr + 3], IQS, (float)run));
}

// ---- k2: scatter blocks (0..NB-1, reading precomputed ge) ∥ node-ect blocks ----
__global__ __launch_bounds__(256) void mid_k(
    const float* __restrict__ x, const float* __restrict__ v,
    const float* __restrict__ lin,
    const int* __restrict__ src, const int* __restrict__ dst,
    const int* __restrict__ ge, int E,
    const int* __restrict__ hist, int* __restrict__ offs,
    int2* __restrict__ epair,
    const int* __restrict__ starts, float* __restrict__ out)
{
    if ((int)blockIdx.x < NB) {
        __shared__ int lcur[BB];
        __shared__ int stot[BB];
        const int tid = threadIdx.x;
        if (tid < BB) {
            int accb = 0, tot = 0;
            for (int b = 0; b < NB; ++b) {
                const int hv = hist[b * BB + tid];
                accb += (b < (int)blockIdx.x) ? hv : 0;
                tot += hv;
            }
            lcur[tid] = accb;
            stot[tid] = tot;
        }
        __syncthreads();
        if (tid == 0) {
            int run = 0;
            for (int i = 0; i < BB; ++i) { const int tv = stot[i]; stot[i] = run; run += tv; }
            if (blockIdx.x == 0) offs[BB] = run;
        }
        __syncthreads();
        if (tid < BB) {
            lcur[tid] += stot[tid];
            if (blockIdx.x == 0) offs[tid] = stot[tid];
        }
        __syncthreads();
        const int per = (E + NB - 1) / NB;
        const int lo = blockIdx.x * per, hi = min(E, lo + per);
        for (int e = lo + tid; e < hi; e += 256) {
            const int pos = atomicAdd(&lcur[ge[e]], 1);
            epair[pos] = int2{src[e], dst[e]};
        }
    } else {
        const int bid = blockIdx.x - NB;
        const int g = bid / CPB_N, c = bid % CPB_N;
        const int s0 = starts[g], s1 = starts[g + 1];
        const int chunk = (s1 - s0 + CPB_N - 1) / CPB_N;
        const int lo = s0 + c * chunk;
        const int hi = min(s1, lo + chunk);
        ect_core(x, v, lin, nullptr, false, lo, hi, g, 1.0f, out);
    }
}

// ---- k3: edge-ect only ----
__global__ __launch_bounds__(256) void edge_k(
    const float* __restrict__ x, const float* __restrict__ v,
    const float* __restrict__ lin, const int2* __restrict__ epair,
    const int* __restrict__ offs, float* __restrict__ out)
{
    const int g = blockIdx.x / CPB_E, c = blockIdx.x % CPB_E;
    const int s0 = offs[g], s1 = offs[g + 1];
    const int chunk = (s1 - s0 + CPB_E - 1) / CPB_E;
    const int lo = s0 + c * chunk;
    const int hi = min(s1, lo + chunk);
    ect_core(x, v, lin, epair, true, lo, hi, g, -1.0f, out);
}

extern "C" void kernel_launch(void* const* d_in, const int* in_sizes, int n_in,
                              void* d_out, int out_size, void* d_ws, size_t ws_size,
                              hipStream_t stream) {
    const float* x   = (const float*)d_in[0];
    const float* v   = (const float*)d_in[1];
    const float* lin = (const float*)d_in[2];
    const int* edge_index = (const int*)d_in[3];
    const int* batch = (const int*)d_in[4];

    const int N = in_sizes[0] / 3;
    const int E = in_sizes[3] / 2;
    const int* src = edge_index;       // edge_index[0][:]
    const int* dst = edge_index + E;   // edge_index[1][:]
    float* out = (float*)d_out;

    char* ws = (char*)d_ws;
    int* starts = (int*)ws;                                   // 65 ints
    int* offs   = (int*)(ws + 512);                           // 65 ints
    int* hist   = (int*)(ws + 1024);                          // NB*BB ints (16 KB)
    int* ge     = (int*)(ws + 65536);                         // E ints
    int2* epair = (int2*)(ws + 65536 + (((size_t)E * 4 + 255) / 256) * 256);  // E int2

    const int nB = (N + 255) / 256;
    prep_k<<<nB + NB, 256, 0, stream>>>(batch, src, N, E, nB, starts, hist, ge, out);
    mid_k<<<NB + BB * CPB_N, 256, 0, stream>>>(x, v, lin, src, dst, ge, E,
                                               hist, offs, epair, starts, out);
    edge_k<<<BB * CPB_E, 256, 0, stream>>>(x, v, lin, epair, offs, out);
}